// Round 1
// baseline (900.312 us; speedup 1.0000x reference)
//
#include <hip/hip_runtime.h>

// Shapes (fixed by the reference)
#define BB 2
#define SS 2048
#define DE 1024
#define DM 1024
#define NH 16
#define DK 64
#define MM (BB*SS)          // 4096 flattened rows

typedef _Float16 HH;
typedef _Float16 half8 __attribute__((ext_vector_type(8)));
typedef float f32x4 __attribute__((ext_vector_type(4)));

// ---------------------------------------------------------------------------
// GEMM: O[m,n] = (OT)( sum_k A[m,k]*W[n,k] + bias[n] )
// A row-major [M,K] (float or fp16), W row-major [N,K] fp32, O [M,N].
// 128x128 tile, BK=32, 4 waves (2x2 of 64x64), mfma_f32_16x16x32_f16.
// ---------------------------------------------------------------------------
template<typename AT, typename OT>
__global__ __launch_bounds__(256) void gemm_bt(const AT* __restrict__ A,
                                               const float* __restrict__ W,
                                               const float* __restrict__ bias,
                                               OT* __restrict__ O,
                                               int M, int N, int K) {
  __shared__ HH As[128][40];   // 32 + 8 pad (row stride 80B -> conflict-free frag reads)
  __shared__ HH Ws[128][40];

  const int tid  = threadIdx.x;
  const int lane = tid & 63;
  const int wid  = tid >> 6;
  const int wr   = wid >> 1, wc = wid & 1;
  const int brow = blockIdx.y * 128;
  const int bcol = blockIdx.x * 128;
  const int g    = lane >> 4;   // k-group
  const int c    = lane & 15;   // row/col within frag

  f32x4 acc[4][4];
  #pragma unroll
  for (int i = 0; i < 4; i++)
    #pragma unroll
    for (int j = 0; j < 4; j++) acc[i][j] = (f32x4)0.0f;

  const int srow = tid >> 1;         // 0..127
  const int scol = (tid & 1) * 16;   // 0 or 16

  for (int k0 = 0; k0 < K; k0 += 32) {
    // stage A tile (convert to fp16)
    {
      const AT* src = A + (size_t)(brow + srow) * K + k0 + scol;
      HH tmp[16];
      if constexpr (sizeof(AT) == 4) {
        #pragma unroll
        for (int v = 0; v < 4; v++) {
          float4 f = *reinterpret_cast<const float4*>(src + v * 4);
          tmp[v*4+0] = (HH)f.x; tmp[v*4+1] = (HH)f.y;
          tmp[v*4+2] = (HH)f.z; tmp[v*4+3] = (HH)f.w;
        }
      } else {
        #pragma unroll
        for (int v = 0; v < 2; v++) {
          half8 hv = *reinterpret_cast<const half8*>(src + v * 8);
          #pragma unroll
          for (int e = 0; e < 8; e++) tmp[v*8+e] = hv[e];
        }
      }
      *reinterpret_cast<half8*>(&As[srow][scol])     = *reinterpret_cast<half8*>(&tmp[0]);
      *reinterpret_cast<half8*>(&As[srow][scol + 8]) = *reinterpret_cast<half8*>(&tmp[8]);
    }
    // stage W tile (convert to fp16)
    {
      const float* src = W + (size_t)(bcol + srow) * K + k0 + scol;
      HH tmp[16];
      #pragma unroll
      for (int v = 0; v < 4; v++) {
        float4 f = *reinterpret_cast<const float4*>(src + v * 4);
        tmp[v*4+0] = (HH)f.x; tmp[v*4+1] = (HH)f.y;
        tmp[v*4+2] = (HH)f.z; tmp[v*4+3] = (HH)f.w;
      }
      *reinterpret_cast<half8*>(&Ws[srow][scol])     = *reinterpret_cast<half8*>(&tmp[0]);
      *reinterpret_cast<half8*>(&Ws[srow][scol + 8]) = *reinterpret_cast<half8*>(&tmp[8]);
    }
    __syncthreads();

    half8 af[4], bf[4];
    #pragma unroll
    for (int i = 0; i < 4; i++)
      af[i] = *reinterpret_cast<half8*>(&As[wr*64 + i*16 + c][g * 8]);
    #pragma unroll
    for (int j = 0; j < 4; j++)
      bf[j] = *reinterpret_cast<half8*>(&Ws[wc*64 + j*16 + c][g * 8]);
    #pragma unroll
    for (int i = 0; i < 4; i++)
      #pragma unroll
      for (int j = 0; j < 4; j++)
        acc[i][j] = __builtin_amdgcn_mfma_f32_16x16x32_f16(af[i], bf[j], acc[i][j], 0, 0, 0);
    __syncthreads();
  }

  // epilogue: + bias, cast, store
  #pragma unroll
  for (int i = 0; i < 4; i++) {
    #pragma unroll
    for (int j = 0; j < 4; j++) {
      const int col = bcol + wc*64 + j*16 + c;
      const float bv = bias[col];
      #pragma unroll
      for (int r = 0; r < 4; r++) {
        const int row = brow + wr*64 + i*16 + g*4 + r;
        O[(size_t)row * N + col] = (OT)(acc[i][j][r] + bv);
      }
    }
  }
}

// ---------------------------------------------------------------------------
// Fused attention: per (b,h) and 64-row Q tile.
// Pass 1: online row max/sum over all KV tiles (scores discarded).
// Pass 2: recompute scores, p = exp(s-m)/l -> write fp32 attn to d_out,
//         stage p fp16 in LDS, accumulate PV. Epilogue writes concat (fp16).
// ---------------------------------------------------------------------------
__global__ __launch_bounds__(256) void attn_fused(
    const HH* __restrict__ Q, const HH* __restrict__ Kh, const HH* __restrict__ Vh,
    const float* __restrict__ mask, float* __restrict__ attn, HH* __restrict__ concat) {
  __shared__ HH Qs[64][72];
  __shared__ HH Ks[64][72];
  __shared__ HH Vt[64][72];   // transposed: [d][kv]
  __shared__ HH Ps[64][72];

  const int tid  = threadIdx.x;
  const int lane = tid & 63;
  const int w    = tid >> 6;       // wave -> q rows [16w, 16w+16)
  const int bh   = blockIdx.y;     // b*16 + h
  const int b    = bh >> 4;
  const int h    = bh & 15;
  const int q0   = blockIdx.x * 64;
  const int g    = lane >> 4;
  const int c    = lane & 15;

  const int srow = tid >> 2;        // 0..63 (4 threads/row)
  const int sc0  = (tid & 3) * 16;

  // stage Q tile once
  {
    const HH* src = Q + (size_t)(b * SS + q0 + srow) * DM + h * DK + sc0;
    *reinterpret_cast<half8*>(&Qs[srow][sc0])     = *reinterpret_cast<const half8*>(src);
    *reinterpret_cast<half8*>(&Qs[srow][sc0 + 8]) = *reinterpret_cast<const half8*>(src + 8);
  }
  __syncthreads();

  half8 aq0 = *reinterpret_cast<half8*>(&Qs[w*16 + c][g * 8]);
  half8 aq1 = *reinterpret_cast<half8*>(&Qs[w*16 + c][32 + g * 8]);

  float m[4], l[4];
  #pragma unroll
  for (int r = 0; r < 4; r++) { m[r] = -3.0e38f; l[r] = 0.0f; }

  // ---------------- pass 1: row max & sum ----------------
  for (int kt = 0; kt < SS / 64; kt++) {
    {
      const HH* src = Kh + (size_t)(b * SS + kt * 64 + srow) * DM + h * DK + sc0;
      *reinterpret_cast<half8*>(&Ks[srow][sc0])     = *reinterpret_cast<const half8*>(src);
      *reinterpret_cast<half8*>(&Ks[srow][sc0 + 8]) = *reinterpret_cast<const half8*>(src + 8);
    }
    __syncthreads();

    f32x4 s[4];
    #pragma unroll
    for (int f = 0; f < 4; f++) {
      half8 bk0 = *reinterpret_cast<half8*>(&Ks[f*16 + c][g * 8]);
      half8 bk1 = *reinterpret_cast<half8*>(&Ks[f*16 + c][32 + g * 8]);
      f32x4 t = (f32x4)0.0f;
      t = __builtin_amdgcn_mfma_f32_16x16x32_f16(aq0, bk0, t, 0, 0, 0);
      t = __builtin_amdgcn_mfma_f32_16x16x32_f16(aq1, bk1, t, 0, 0, 0);
      const float mv = mask[(size_t)b * SS + kt * 64 + f * 16 + c];
      const float madd = (1.0f - mv) * -1e9f;
      #pragma unroll
      for (int r = 0; r < 4; r++) t[r] += madd;
      s[f] = t;
    }
    #pragma unroll
    for (int r = 0; r < 4; r++) {
      float tm = fmaxf(fmaxf(s[0][r], s[1][r]), fmaxf(s[2][r], s[3][r]));
      for (int off = 1; off < 16; off <<= 1) tm = fmaxf(tm, __shfl_xor(tm, off));
      const float mn = fmaxf(m[r], tm);
      float rs = 0.0f;
      #pragma unroll
      for (int f = 0; f < 4; f++) rs += __expf(s[f][r] - mn);
      for (int off = 1; off < 16; off <<= 1) rs += __shfl_xor(rs, off);
      l[r] = l[r] * __expf(m[r] - mn) + rs;
      m[r] = mn;
    }
    __syncthreads();
  }

  float invl[4];
  #pragma unroll
  for (int r = 0; r < 4; r++) invl[r] = 1.0f / l[r];

  f32x4 pv[4];
  #pragma unroll
  for (int f = 0; f < 4; f++) pv[f] = (f32x4)0.0f;

  // ---------------- pass 2: recompute, write attn, PV ----------------
  for (int kt = 0; kt < SS / 64; kt++) {
    {
      const HH* src = Kh + (size_t)(b * SS + kt * 64 + srow) * DM + h * DK + sc0;
      *reinterpret_cast<half8*>(&Ks[srow][sc0])     = *reinterpret_cast<const half8*>(src);
      *reinterpret_cast<half8*>(&Ks[srow][sc0 + 8]) = *reinterpret_cast<const half8*>(src + 8);
      const HH* vsrc = Vh + (size_t)(b * SS + kt * 64 + srow) * DM + h * DK + sc0;
      half8 v0 = *reinterpret_cast<const half8*>(vsrc);
      half8 v1 = *reinterpret_cast<const half8*>(vsrc + 8);
      #pragma unroll
      for (int e = 0; e < 8; e++) Vt[sc0 + e][srow] = v0[e];
      #pragma unroll
      for (int e = 0; e < 8; e++) Vt[sc0 + 8 + e][srow] = v1[e];
    }
    __syncthreads();

    #pragma unroll
    for (int f = 0; f < 4; f++) {
      half8 bk0 = *reinterpret_cast<half8*>(&Ks[f*16 + c][g * 8]);
      half8 bk1 = *reinterpret_cast<half8*>(&Ks[f*16 + c][32 + g * 8]);
      f32x4 t = (f32x4)0.0f;
      t = __builtin_amdgcn_mfma_f32_16x16x32_f16(aq0, bk0, t, 0, 0, 0);
      t = __builtin_amdgcn_mfma_f32_16x16x32_f16(aq1, bk1, t, 0, 0, 0);
      const float mv = mask[(size_t)b * SS + kt * 64 + f * 16 + c];
      const float madd = (1.0f - mv) * -1e9f;
      #pragma unroll
      for (int r = 0; r < 4; r++) {
        const float p = __expf(t[r] + madd - m[r]) * invl[r];
        const int qrow = w * 16 + g * 4 + r;
        attn[((size_t)bh * SS + (q0 + qrow)) * SS + kt * 64 + f * 16 + c] = p;
        Ps[qrow][f * 16 + c] = (HH)p;
      }
    }
    __syncthreads();

    half8 ap0 = *reinterpret_cast<half8*>(&Ps[w*16 + c][g * 8]);
    half8 ap1 = *reinterpret_cast<half8*>(&Ps[w*16 + c][32 + g * 8]);
    #pragma unroll
    for (int f = 0; f < 4; f++) {
      half8 bv0 = *reinterpret_cast<half8*>(&Vt[f*16 + c][g * 8]);
      half8 bv1 = *reinterpret_cast<half8*>(&Vt[f*16 + c][32 + g * 8]);
      pv[f] = __builtin_amdgcn_mfma_f32_16x16x32_f16(ap0, bv0, pv[f], 0, 0, 0);
      pv[f] = __builtin_amdgcn_mfma_f32_16x16x32_f16(ap1, bv1, pv[f], 0, 0, 0);
    }
    __syncthreads();
  }

  // epilogue: write concat [B*S, DM] fp16
  #pragma unroll
  for (int f = 0; f < 4; f++) {
    #pragma unroll
    for (int r = 0; r < 4; r++) {
      const int qrow = w * 16 + g * 4 + r;
      concat[(size_t)(b * SS + q0 + qrow) * DM + h * DK + f * 16 + c] = (HH)pv[f][r];
    }
  }
}

// ---------------------------------------------------------------------------
extern "C" void kernel_launch(void* const* d_in, const int* in_sizes, int n_in,
                              void* d_out, int out_size, void* d_ws, size_t ws_size,
                              hipStream_t stream) {
  const float* query = (const float*)d_in[0];
  const float* embeds = (const float*)d_in[1];
  const float* mask  = (const float*)d_in[2];
  const float* wq_w = (const float*)d_in[3];
  const float* wq_b = (const float*)d_in[4];
  const float* wk_w = (const float*)d_in[5];
  const float* wk_b = (const float*)d_in[6];
  const float* wv_w = (const float*)d_in[7];
  const float* wv_b = (const float*)d_in[8];
  const float* wo_w = (const float*)d_in[9];
  const float* wo_b = (const float*)d_in[10];

  // d_out: out fp32 [B,S,DE] then attn fp32 [B,H,S,S]
  float* out  = (float*)d_out;
  float* attn = out + (size_t)MM * DE;

  // workspace: Q, K, V, concat as fp16 [MM, DM] (8 MB each, 32 MB total)
  HH* Qw = (HH*)d_ws;
  HH* Kw = Qw + (size_t)MM * DM;
  HH* Vw = Kw + (size_t)MM * DM;
  HH* Cc = Vw + (size_t)MM * DM;

  dim3 gg(DM / 128, MM / 128);   // (8, 32)
  gemm_bt<float, HH><<<gg, 256, 0, stream>>>(query,  wq_w, wq_b, Qw, MM, DM, DE);
  gemm_bt<float, HH><<<gg, 256, 0, stream>>>(embeds, wk_w, wk_b, Kw, MM, DM, DE);
  gemm_bt<float, HH><<<gg, 256, 0, stream>>>(embeds, wv_w, wv_b, Vw, MM, DM, DE);

  dim3 ga(SS / 64, BB * NH);     // (32, 32)
  attn_fused<<<ga, 256, 0, stream>>>(Qw, Kw, Vw, mask, attn, Cc);

  gemm_bt<HH, float><<<gg, 256, 0, stream>>>(Cc, wo_w, wo_b, out, MM, DE, DM);
}

// Round 3
// 785.360 us; speedup vs baseline: 1.1464x; 1.1464x over previous
//
#include <hip/hip_runtime.h>

// Shapes (fixed by the reference)
#define BB 2
#define SS 2048
#define DE 1024
#define DM 1024
#define NH 16
#define DK 64
#define MM (BB*SS)          // 4096 flattened rows

typedef _Float16 HH;
typedef _Float16 half4 __attribute__((ext_vector_type(4)));
typedef _Float16 half8 __attribute__((ext_vector_type(8)));
typedef float f32x4 __attribute__((ext_vector_type(4)));

// async global->LDS, 16B per lane; LDS dest = wave-uniform base + lane*16
__device__ __forceinline__ void gload_lds16(const void* g, void* l) {
  __builtin_amdgcn_global_load_lds(
      (const __attribute__((address_space(1))) uint32_t*)g,
      (__attribute__((address_space(3))) uint32_t*)l, 16, 0, 0);
}

// ---------------------------------------------------------------------------
// fp32 -> fp16 conversion for 6 tensors (query, embeds, wq, wk, wv, wo)
// ---------------------------------------------------------------------------
__global__ __launch_bounds__(256) void cvt6(
    const float* __restrict__ q,  const float* __restrict__ e,
    const float* __restrict__ wq, const float* __restrict__ wk,
    const float* __restrict__ wv, const float* __restrict__ wo,
    HH* qh, HH* eh, HH* wqh, HH* wkh, HH* wvh, HH* woh) {
  const float* s; HH* d; int n4;
  switch (blockIdx.y) {
    case 0:  s = q;  d = qh;  n4 = MM * DE / 4; break;
    case 1:  s = e;  d = eh;  n4 = MM * DE / 4; break;
    case 2:  s = wq; d = wqh; n4 = DM * DE / 4; break;
    case 3:  s = wk; d = wkh; n4 = DM * DE / 4; break;
    case 4:  s = wv; d = wvh; n4 = DM * DE / 4; break;
    default: s = wo; d = woh; n4 = DM * DE / 4; break;
  }
  for (int i = blockIdx.x * 256 + threadIdx.x; i < n4; i += gridDim.x * 256) {
    float4 f = reinterpret_cast<const float4*>(s)[i];
    half4 h; h[0] = (HH)f.x; h[1] = (HH)f.y; h[2] = (HH)f.z; h[3] = (HH)f.w;
    *reinterpret_cast<half4*>(&d[(size_t)i * 4]) = h;
  }
}

// ---------------------------------------------------------------------------
// m97-structure GEMM body: O[m,n] = A[m,:] . W[n,:] + bias[n]
// A,W fp16 row-major [.,1024], K=N=1024, M=4096. 128x128 tile, BK=32,
// 4 waves (2x2 of 64x64), global_load_lds dwordx4, linear LDS.
// ---------------------------------------------------------------------------
template<typename OT>
__device__ __forceinline__ void gemm_body(const HH* __restrict__ A,
                                          const HH* __restrict__ W,
                                          const float* __restrict__ bias,
                                          OT* __restrict__ O) {
  __shared__ alignas(16) HH As[128][32];
  __shared__ alignas(16) HH Ws[128][32];

  const int tid  = threadIdx.x;
  const int lane = tid & 63;
  const int wid  = tid >> 6;
  const int wr   = wid >> 1, wc = wid & 1;
  const int brow = blockIdx.y * 128;
  const int bcol = blockIdx.x * 128;
  const int g    = lane >> 4;
  const int c    = lane & 15;

  f32x4 acc[4][4] = {};

  // staging map: thread t covers LDS bytes [t*16, t*16+16) of each 4KB half
  const int lr = tid >> 2;          // row 0..63 within half-tile
  const int lc = (tid & 3) * 8;     // halves-col 0/8/16/24
  const HH* a0 = A + (size_t)(brow + lr) * 1024 + lc;
  const HH* w0 = W + (size_t)(bcol + lr) * 1024 + lc;
  char* ldsA = (char*)As + tid * 16;
  char* ldsW = (char*)Ws + tid * 16;

  for (int k0 = 0; k0 < 1024; k0 += 32) {
    gload_lds16(a0 + k0,             ldsA);
    gload_lds16(a0 + 64 * 1024 + k0, ldsA + 4096);
    gload_lds16(w0 + k0,             ldsW);
    gload_lds16(w0 + 64 * 1024 + k0, ldsW + 4096);
    __syncthreads();

    half8 af[4], bf[4];
    #pragma unroll
    for (int i = 0; i < 4; i++)
      af[i] = *reinterpret_cast<half8*>(&As[wr * 64 + i * 16 + c][g * 8]);
    #pragma unroll
    for (int j = 0; j < 4; j++)
      bf[j] = *reinterpret_cast<half8*>(&Ws[wc * 64 + j * 16 + c][g * 8]);
    #pragma unroll
    for (int i = 0; i < 4; i++)
      #pragma unroll
      for (int j = 0; j < 4; j++)
        acc[i][j] = __builtin_amdgcn_mfma_f32_16x16x32_f16(af[i], bf[j], acc[i][j], 0, 0, 0);
    __syncthreads();
  }

  #pragma unroll
  for (int i = 0; i < 4; i++) {
    #pragma unroll
    for (int j = 0; j < 4; j++) {
      const int col = bcol + wc * 64 + j * 16 + c;
      const float bv = bias[col];
      #pragma unroll
      for (int r = 0; r < 4; r++) {
        const int row = brow + wr * 64 + i * 16 + g * 4 + r;
        O[(size_t)row * 1024 + col] = (OT)(acc[i][j][r] + bv);
      }
    }
  }
}

// fused QKV projection: z picks (A, W, bias, O)
__global__ __launch_bounds__(256) void gemm_qkv(
    const HH* __restrict__ Aq, const HH* __restrict__ Ae,
    const HH* __restrict__ Wq, const HH* __restrict__ Wk, const HH* __restrict__ Wv,
    const float* __restrict__ bq, const float* __restrict__ bk, const float* __restrict__ bv,
    HH* Oq, HH* Ok, HH* Ov) {
  const HH* A; const HH* W; const float* bias; HH* O;
  switch (blockIdx.z) {
    case 0:  A = Aq; W = Wq; bias = bq; O = Oq; break;
    case 1:  A = Ae; W = Wk; bias = bk; O = Ok; break;
    default: A = Ae; W = Wv; bias = bv; O = Ov; break;
  }
  gemm_body<HH>(A, W, bias, O);
}

// output projection (fp32 out)
__global__ __launch_bounds__(256) void gemm_o(
    const HH* __restrict__ A, const HH* __restrict__ W,
    const float* __restrict__ bias, float* __restrict__ O) {
  gemm_body<float>(A, W, bias, O);
}

// ---------------------------------------------------------------------------
// Fused attention: per (b,h) and 64-row Q tile.
// Pass 1: online row max/sum over all KV tiles (scores discarded).
// Pass 2: recompute scores, p = exp(s-m)/l -> write fp32 attn (nontemporal),
//         stage p fp16 in LDS, accumulate PV. Epilogue writes concat fp16.
// ---------------------------------------------------------------------------
__global__ __launch_bounds__(256) void attn_fused(
    const HH* __restrict__ Q, const HH* __restrict__ Kh, const HH* __restrict__ Vh,
    const float* __restrict__ mask, float* __restrict__ attn, HH* __restrict__ concat) {
  __shared__ HH Qs[64][72];
  __shared__ HH Ks[64][72];
  __shared__ HH Vt[64][72];   // transposed: [d][kv]
  __shared__ HH Ps[64][72];

  const int tid  = threadIdx.x;
  const int lane = tid & 63;
  const int w    = tid >> 6;
  const int bh   = blockIdx.y;
  const int b    = bh >> 4;
  const int h    = bh & 15;
  const int q0   = blockIdx.x * 64;
  const int g    = lane >> 4;
  const int c    = lane & 15;

  const int srow = tid >> 2;
  const int sc0  = (tid & 3) * 16;

  {
    const HH* src = Q + (size_t)(b * SS + q0 + srow) * DM + h * DK + sc0;
    *reinterpret_cast<half8*>(&Qs[srow][sc0])     = *reinterpret_cast<const half8*>(src);
    *reinterpret_cast<half8*>(&Qs[srow][sc0 + 8]) = *reinterpret_cast<const half8*>(src + 8);
  }
  __syncthreads();

  half8 aq0 = *reinterpret_cast<half8*>(&Qs[w * 16 + c][g * 8]);
  half8 aq1 = *reinterpret_cast<half8*>(&Qs[w * 16 + c][32 + g * 8]);

  float m[4], l[4];
  #pragma unroll
  for (int r = 0; r < 4; r++) { m[r] = -3.0e38f; l[r] = 0.0f; }

  // ---------------- pass 1: row max & sum ----------------
  for (int kt = 0; kt < SS / 64; kt++) {
    {
      const HH* src = Kh + (size_t)(b * SS + kt * 64 + srow) * DM + h * DK + sc0;
      *reinterpret_cast<half8*>(&Ks[srow][sc0])     = *reinterpret_cast<const half8*>(src);
      *reinterpret_cast<half8*>(&Ks[srow][sc0 + 8]) = *reinterpret_cast<const half8*>(src + 8);
    }
    __syncthreads();

    f32x4 s[4];
    #pragma unroll
    for (int f = 0; f < 4; f++) {
      half8 bk0 = *reinterpret_cast<half8*>(&Ks[f * 16 + c][g * 8]);
      half8 bk1 = *reinterpret_cast<half8*>(&Ks[f * 16 + c][32 + g * 8]);
      f32x4 t = (f32x4)0.0f;
      t = __builtin_amdgcn_mfma_f32_16x16x32_f16(aq0, bk0, t, 0, 0, 0);
      t = __builtin_amdgcn_mfma_f32_16x16x32_f16(aq1, bk1, t, 0, 0, 0);
      const float mv = mask[(size_t)b * SS + kt * 64 + f * 16 + c];
      const float madd = (1.0f - mv) * -1e9f;
      #pragma unroll
      for (int r = 0; r < 4; r++) t[r] += madd;
      s[f] = t;
    }
    #pragma unroll
    for (int r = 0; r < 4; r++) {
      float tm = fmaxf(fmaxf(s[0][r], s[1][r]), fmaxf(s[2][r], s[3][r]));
      for (int off = 1; off < 16; off <<= 1) tm = fmaxf(tm, __shfl_xor(tm, off));
      const float mn = fmaxf(m[r], tm);
      float rs = 0.0f;
      #pragma unroll
      for (int f = 0; f < 4; f++) rs += __expf(s[f][r] - mn);
      for (int off = 1; off < 16; off <<= 1) rs += __shfl_xor(rs, off);
      l[r] = l[r] * __expf(m[r] - mn) + rs;
      m[r] = mn;
    }
    __syncthreads();
  }

  float invl[4];
  #pragma unroll
  for (int r = 0; r < 4; r++) invl[r] = 1.0f / l[r];

  f32x4 pv[4];
  #pragma unroll
  for (int f = 0; f < 4; f++) pv[f] = (f32x4)0.0f;

  // ---------------- pass 2: recompute, write attn, PV ----------------
  for (int kt = 0; kt < SS / 64; kt++) {
    {
      const HH* src = Kh + (size_t)(b * SS + kt * 64 + srow) * DM + h * DK + sc0;
      *reinterpret_cast<half8*>(&Ks[srow][sc0])     = *reinterpret_cast<const half8*>(src);
      *reinterpret_cast<half8*>(&Ks[srow][sc0 + 8]) = *reinterpret_cast<const half8*>(src + 8);
      const HH* vsrc = Vh + (size_t)(b * SS + kt * 64 + srow) * DM + h * DK + sc0;
      half8 v0 = *reinterpret_cast<const half8*>(vsrc);
      half8 v1 = *reinterpret_cast<const half8*>(vsrc + 8);
      #pragma unroll
      for (int e = 0; e < 8; e++) Vt[sc0 + e][srow] = v0[e];
      #pragma unroll
      for (int e = 0; e < 8; e++) Vt[sc0 + 8 + e][srow] = v1[e];
    }
    __syncthreads();

    #pragma unroll
    for (int f = 0; f < 4; f++) {
      half8 bk0 = *reinterpret_cast<half8*>(&Ks[f * 16 + c][g * 8]);
      half8 bk1 = *reinterpret_cast<half8*>(&Ks[f * 16 + c][32 + g * 8]);
      f32x4 t = (f32x4)0.0f;
      t = __builtin_amdgcn_mfma_f32_16x16x32_f16(aq0, bk0, t, 0, 0, 0);
      t = __builtin_amdgcn_mfma_f32_16x16x32_f16(aq1, bk1, t, 0, 0, 0);
      const float mv = mask[(size_t)b * SS + kt * 64 + f * 16 + c];
      const float madd = (1.0f - mv) * -1e9f;
      #pragma unroll
      for (int r = 0; r < 4; r++) {
        const float p = __expf(t[r] + madd - m[r]) * invl[r];
        const int qrow = w * 16 + g * 4 + r;
        __builtin_nontemporal_store(
            p, &attn[((size_t)bh * SS + (q0 + qrow)) * SS + kt * 64 + f * 16 + c]);
        Ps[qrow][f * 16 + c] = (HH)p;
      }
    }
    __syncthreads();

    half8 ap0 = *reinterpret_cast<half8*>(&Ps[w * 16 + c][g * 8]);
    half8 ap1 = *reinterpret_cast<half8*>(&Ps[w * 16 + c][32 + g * 8]);
    #pragma unroll
    for (int f = 0; f < 4; f++) {
      half8 bv0 = *reinterpret_cast<half8*>(&Vt[f * 16 + c][g * 8]);
      half8 bv1 = *reinterpret_cast<half8*>(&Vt[f * 16 + c][32 + g * 8]);
      pv[f] = __builtin_amdgcn_mfma_f32_16x16x32_f16(ap0, bv0, pv[f], 0, 0, 0);
      pv[f] = __builtin_amdgcn_mfma_f32_16x16x32_f16(ap1, bv1, pv[f], 0, 0, 0);
    }
    __syncthreads();
  }

  #pragma unroll
  for (int f = 0; f < 4; f++) {
    #pragma unroll
    for (int r = 0; r < 4; r++) {
      const int qrow = w * 16 + g * 4 + r;
      concat[(size_t)(b * SS + q0 + qrow) * DM + h * DK + f * 16 + c] = (HH)pv[f][r];
    }
  }
}

// ---------------------------------------------------------------------------
extern "C" void kernel_launch(void* const* d_in, const int* in_sizes, int n_in,
                              void* d_out, int out_size, void* d_ws, size_t ws_size,
                              hipStream_t stream) {
  const float* query  = (const float*)d_in[0];
  const float* embeds = (const float*)d_in[1];
  const float* mask   = (const float*)d_in[2];
  const float* wq_w = (const float*)d_in[3];
  const float* wq_b = (const float*)d_in[4];
  const float* wk_w = (const float*)d_in[5];
  const float* wk_b = (const float*)d_in[6];
  const float* wv_w = (const float*)d_in[7];
  const float* wv_b = (const float*)d_in[8];
  const float* wo_w = (const float*)d_in[9];
  const float* wo_b = (const float*)d_in[10];

  float* out  = (float*)d_out;
  float* attn = out + (size_t)MM * DE;

  // workspace (fp16): Qh, Eh [MM*DE]; Wqh..Woh [DM*DE]; Qw,Kw,Vw,Cc [MM*DM]
  HH* Qh  = (HH*)d_ws;
  HH* Eh  = Qh  + (size_t)MM * DE;
  HH* Wqh = Eh  + (size_t)MM * DE;
  HH* Wkh = Wqh + (size_t)DM * DE;
  HH* Wvh = Wkh + (size_t)DM * DE;
  HH* Woh = Wvh + (size_t)DM * DE;
  HH* Qw  = Woh + (size_t)DM * DE;
  HH* Kw  = Qw  + (size_t)MM * DM;
  HH* Vw  = Kw  + (size_t)MM * DM;
  HH* Cc  = Vw  + (size_t)MM * DM;

  cvt6<<<dim3(1024, 6), 256, 0, stream>>>(query, embeds, wq_w, wk_w, wv_w, wo_w,
                                          Qh, Eh, Wqh, Wkh, Wvh, Woh);

  gemm_qkv<<<dim3(8, 32, 3), 256, 0, stream>>>(Qh, Eh, Wqh, Wkh, Wvh,
                                               wq_b, wk_b, wv_b, Qw, Kw, Vw);

  attn_fused<<<dim3(SS / 64, BB * NH), 256, 0, stream>>>(Qw, Kw, Vw, mask, attn, Cc);

  gemm_o<<<dim3(8, 32), 256, 0, stream>>>(Cc, Woh, wo_b, out);
}